// Round 8
// baseline (1294.439 us; speedup 1.0000x reference)
//
#include <hip/hip_runtime.h>

// DeepAR forward: B=32, L_IN=336, L_OUT=48, N=512, COV=4, EMB=32, H=64
// T = 383 steps (t=0..382), BN = 16384 sequences.
//
// R9: wave-specialized cross-layer pipeline, 1 WG/CU, 256-VGPR regime.
//  - Grid 256 WGs x 512 threads (= CU count, no tail). 64 seqs/WG.
//    __launch_bounds__(512,2): 2 waves/SIMD -> 256 VGPR budget. The 128-VGPR
//    cap of the old 2x256 config was the binding constraint (R3/R4/R5 all
//    spilled); this config removes it without raising per-wave live state.
//  - Waves 0-3 = layer 0 (jt = wv), waves 4-7 = layer 1 (jt = wv-4), software
//    pipeline: phase p computes L0(t=p) and L1(t'=p-1). ONE barrier/phase
//    (385 total vs R8's 766). h0/h1/x regions ping-pong by parity; every
//    producer->consumer and anti-dep pair is separated by the phase barrier.
//  - Structural anti-phase: each SIMD hosts 1 L0 + 1 L1 wave; L0's
//    trans-heavy epilogue overlaps L1's MFMA/DS phase (m114 co-schedule).
//  - AST=272 (dword stride 136 = 8 mod 32): b128 A-reads and b64 h-stores
//    are exactly min-covered per bank (R8's stride-116 patterns were not;
//    measured conflicts ROSE to 5.3e7 -> this attacks them).
//  - Both layers swapped-operand (W as A-op, frag lane-maps are role-
//    symmetric): lane owns 4 consecutive hidden units -> cvt_pk + b64 store.
//    L0 bias via constant-1.0 cols; L1 bias via f32 C-init (bi1v).
//  - W1 frags in LDS are wave-private (written and read by the same wave).
//
// Row layout (shorts, AST=272):
//  [h0_e 0-63 | h0_o 64-127 | h1_e 128-191 | h1_o 192-255 |
//   x_e: 256 prev,257-260 cov,261-262 =1.0 | 263 pad |
//   x_o: 264 prev,265-268 cov,269-270 =1.0 | 271 pad]
//  x-frag reads span 32 cols past the region base; all overrun cols hit
//  zero weights in bf0[g][2] (kk>=7 zero), so the overlap is numerically inert.

#define AST 272
#define NPH 385
#define LOG2E 1.44269504088896340736f

typedef __attribute__((ext_vector_type(8))) short short8;
typedef __attribute__((ext_vector_type(2))) unsigned int uint2v;
typedef __attribute__((ext_vector_type(4))) float floatx4;

__device__ __forceinline__ unsigned short f2bf(float f){   // RNE (prologue)
  union { float f; unsigned u; } v; v.f = f;
  unsigned u = v.u + 0x7fffu + ((v.u >> 16) & 1u);
  return (unsigned short)(u >> 16);
}
__device__ __forceinline__ unsigned short f2bf_fast(float f){  // round-half-up
  union { float f; unsigned u; } v; v.f = f;
  return (unsigned short)((v.u + 0x8000u) >> 16);
}
__device__ __forceinline__ float bf2f(unsigned short b){
  union { unsigned u; float f; } v; v.u = ((unsigned)b) << 16; return v.f;
}

// LSTM cell epilogue on log2e-prescaled pre-activations.
// iv,fv,ov = pre-act * log2e; gv = pre-act * 2*log2e. Updates c, returns h.
__device__ __forceinline__ float lstm_h(float iv, float fv, float gv, float ov, float& c){
  const float ea = __builtin_amdgcn_exp2f(-fv);   // e^-f
  const float eb = __builtin_amdgcn_exp2f(-iv);   // e^-i
  const float ec = __builtin_amdgcn_exp2f(-gv);   // e^-2g
  const float eo = __builtin_amdgcn_exp2f(-ov);   // e^-o
  const float A = 1.f + ea, B = 1.f + eb, C = 1.f + ec, D = 1.f + eo;
  const float BC = B * C;
  const float num = c * BC + A * (2.f - C);       // sig(f)c + sig(i)tanh(g), * A*BC
  const float cn = num * __builtin_amdgcn_rcpf(A * BC);
  c = cn;
  const float arg = fminf(cn * (-2.f * LOG2E), 126.f);   // clamp: c<<0 overflow guard
  const float E = 1.f + __builtin_amdgcn_exp2f(arg);     // 1 + e^-2c
  return (2.f - E) * __builtin_amdgcn_rcpf(D * E);       // sig(o)*tanh(c)
}

__global__ __launch_bounds__(512, 2) void deepar_kernel(
    const float* __restrict__ hist, const float* __restrict__ fut,
    const float* __restrict__ embW, const float* __restrict__ embB,
    const float* __restrict__ Wih0, const float* __restrict__ Whh0,
    const float* __restrict__ bih0, const float* __restrict__ bhh0,
    const float* __restrict__ Wih1, const float* __restrict__ Whh1,
    const float* __restrict__ bih1, const float* __restrict__ bhh1,
    const float* __restrict__ headW, const float* __restrict__ headB,
    float* __restrict__ outp)
{
  const int tid  = threadIdx.x;
  const int lane = tid & 63;
  const int wv   = tid >> 6;        // 0..7
  const int l15  = lane & 15;
  const int quad = lane >> 4;       // 0..3
  const int koff = quad * 8;
  const bool isL0 = (wv < 4);
  const int jt    = wv & 3;               // hidden 16-block within this wave's layer
  const int jbase = jt * 16 + quad * 4;   // first of this lane's 4 hidden units

  const int b  = blockIdx.x >> 3;            // batch (32)
  const int n0 = (blockIdx.x & 7) * 64;      // first series index (8 x 64 = 512)

  __shared__ __align__(16) unsigned short A[64 * AST];     // 34816 B
  __shared__ __align__(16) unsigned short W1[64 * 64 * 8]; // 65536 B, frag-ordered
  __shared__ float HW[128];                                // 512 B

  for (int i = tid; i < 64 * AST; i += 512) A[i] = 0;
  if (tid < 128) HW[tid] = headW[tid];
  __syncthreads();   // zero-fill visible before 1.0-cols + x(0) staging
  if (tid < 64){
    A[tid * AST + 261] = 0x3f80;  A[tid * AST + 262] = 0x3f80;   // x_e 1.0 cols
    A[tid * AST + 269] = 0x3f80;  A[tid * AST + 270] = 0x3f80;   // x_o 1.0 cols
  }
  const float hb0 = headB[0], hb1 = headB[1];

  // ---- weights: L0 waves -> bf0 regs; L1 waves -> W1 LDS (wave-private) ----
  // frag (16x16x32): lane holds elem (idx=lane&15, k=quad*8+j) — identical
  // map for A- and B-roles. Gate pre-scale: i,f,o *log2e; g *2*log2e.
  short8  bf0[4][3];   // L0 only: kf0,1 = Whh0; kf2 = input cols
  floatx4 bi1v[4];     // L1 only: bias for this lane's 4 hidden units, per gate
  #pragma unroll
  for (int g = 0; g < 4; ++g){
    const float gsc = (g == 2) ? 2.f * LOG2E : LOG2E;
    const int r = g * 64 + jt * 16 + l15;     // gate row 0..255
    if (isL0){
      float u = 0.f, bb = bih0[r] + bhh0[r];
      #pragma unroll
      for (int e = 0; e < 32; ++e){
        float wval = Wih0[r * 36 + e];
        u  += wval * embW[e];
        bb += wval * embB[e];
      }
      const float bbs = bb * gsc;
      const unsigned short bbq = f2bf(bbs);        // bias hi (bf16)
      const float bbr = bbs - bf2f(bbq);           // bias residual
      #pragma unroll
      for (int kf = 0; kf < 2; ++kf)
        #pragma unroll
        for (int j = 0; j < 8; ++j)
          bf0[g][kf][j] = (short)f2bf(Whh0[r * 64 + kf * 32 + koff + j] * gsc);
      #pragma unroll
      for (int j = 0; j < 8; ++j){
        int kk = koff + j;          // local k within x frag
        unsigned short q16;
        if (kk == 5)      q16 = bbq;                               // * 1.0 col
        else if (kk == 6) q16 = f2bf(bbr);                         // * 1.0 col
        else {
          float v = 0.f;
          if (kk == 0) v = u;                                      // prev -> u[r]
          else if (kk >= 1 && kk <= 4) v = Wih0[r * 36 + 32 + (kk - 1)];
          q16 = f2bf(v * gsc);
        }
        bf0[g][2][j] = (short)q16;
      }
    } else {
      #pragma unroll
      for (int q = 0; q < 4; ++q){
        const int re = g * 64 + jt * 16 + quad * 4 + q;
        bi1v[g][q] = (bih1[re] + bhh1[re]) * gsc;
      }
      #pragma unroll
      for (int kf = 0; kf < 4; ++kf){
        const float* src = (kf < 2) ? (Wih1 + r * 64 + kf * 32)
                                    : (Whh1 + r * 64 + (kf - 2) * 32);
        short8 w;
        #pragma unroll
        for (int j = 0; j < 8; ++j)
          w[j] = (short)f2bf(src[koff + j] * gsc);
        *(short8*)&W1[(((jt * 16 + g * 4 + kf) * 64) + lane) * 8] = w;
      }
    }
  }

  // ---- input staging (prev: wave 0; cov: waves 1-4) ----
  const bool isPrev = (tid < 64);
  const bool isCov  = (tid >= 64 && tid < 320);
  int ss = 0, cc = 0;
  if (isPrev){ ss = tid; cc = 0; }
  if (isCov) { ss = (tid - 64) >> 2; cc = 1 + ((tid - 64) & 3); }
  const int myN = n0 + ss;

  auto loadSlab = [&](int tt) -> float {
    if (isPrev){
      int l = tt; if (l > 383) l = 383;
      return (l < 336) ? hist[(((size_t)b * 336 + l) * 512 + myN) * 5]
                       : fut [(((size_t)b * 48 + (l - 336)) * 512 + myN) * 5];
    } else if (isCov){
      int l = tt + 1; if (l > 383) l = 383;
      return (l < 336) ? hist[(((size_t)b * 336 + l) * 512 + myN) * 5 + cc]
                       : fut [(((size_t)b * 48 + (l - 336)) * 512 + myN) * 5 + cc];
    }
    return 0.f;
  };

  float rCur = loadSlab(0);
  if (isPrev || isCov) A[ss * AST + 256 + cc] = f2bf(rCur);   // x(0) -> x_e
  rCur = loadSlab(1);   // holds x(p+1) entering each phase

  float cst[16];   // c-state: 16 cells/lane (own layer only)
  #pragma unroll
  for (int i = 0; i < 16; ++i) cst[i] = 0.f;

  // head decomposition (all 512 threads; 8 threads/seq)
  const int hd_hs   = tid >> 3;          // 0..63
  const int hd_outc = (tid >> 2) & 1;
  const int hd_part = tid & 3;

  __syncthreads();

  for (int p = 0; p < NPH; ++p){
    const int par = p & 1;
    const float rNxt = loadSlab(p + 2);                       // issue early
    if (isPrev || isCov)
      A[ss * AST + 256 + (par ^ 1) * 8 + cc] = f2bf_fast(rCur);  // x(p+1)

    const int h0rd = (par ^ 1) * 64;   // h0(p-1) region

    if (isL0){
      // ========== layer 0: t = p (reads h0(p-1), x(p); writes h0(p)) =====
      if (p < 383){
        const int h0wr = par * 64;
        const int xrd  = 256 + par * 8;
        floatx4 acc[4][4];
        #pragma unroll
        for (int g = 0; g < 4; ++g)
          #pragma unroll
          for (int mt = 0; mt < 4; ++mt){
            floatx4 z = {0.f, 0.f, 0.f, 0.f};   // bias rides the 1.0 cols
            acc[g][mt] = z;
          }
        const int c0off[3] = { h0rd, h0rd + 32, xrd };
        #pragma unroll
        for (int mt = 0; mt < 4; ++mt){
          #pragma unroll
          for (int kf = 0; kf < 3; ++kf){
            short8 af = *(const short8*)&A[(mt * 16 + l15) * AST + c0off[kf] + koff];
            #pragma unroll
            for (int g = 0; g < 4; ++g)
              acc[g][mt] = __builtin_amdgcn_mfma_f32_16x16x32_bf16(bf0[g][kf], af, acc[g][mt], 0, 0, 0);
          }
        }
        // D (swapped): col=l15=seq, row=quad*4+q=hidden jbase+q
        #pragma unroll
        for (int mt = 0; mt < 4; ++mt){
          float hn[4];
          #pragma unroll
          for (int q = 0; q < 4; ++q)
            hn[q] = lstm_h(acc[0][mt][q], acc[1][mt][q], acc[2][mt][q], acc[3][mt][q], cst[mt * 4 + q]);
          uint2v pk;
          asm("v_cvt_pk_bf16_f32 %0, %1, %2" : "=v"(pk.x) : "v"(hn[0]), "v"(hn[1]));
          asm("v_cvt_pk_bf16_f32 %0, %1, %2" : "=v"(pk.y) : "v"(hn[2]), "v"(hn[3]));
          *(uint2v*)&A[(mt * 16 + l15) * AST + h0wr + jbase] = pk;   // h0(p)
        }
      }
    } else {
      // ===== layer 1: t' = p-1 (reads h0(p-1), h1(p-2); writes h1(p-1)) ==
      if (p >= 1 && p < 384){
        const int h1rd = 128 + par * 64;
        const int h1wr = 128 + (par ^ 1) * 64;
        floatx4 acc[4][4];
        #pragma unroll
        for (int g = 0; g < 4; ++g)
          #pragma unroll
          for (int mt = 0; mt < 4; ++mt)
            acc[g][mt] = bi1v[g];
        const int c1off[4] = { h0rd, h0rd + 32, h1rd, h1rd + 32 };
        #pragma unroll
        for (int kf = 0; kf < 4; ++kf){
          short8 wfr[4];
          #pragma unroll
          for (int g = 0; g < 4; ++g)
            wfr[g] = *(const short8*)&W1[(((jt * 16 + g * 4 + kf) * 64) + lane) * 8];
          #pragma unroll
          for (int mt = 0; mt < 4; ++mt){
            short8 af = *(const short8*)&A[(mt * 16 + l15) * AST + c1off[kf] + koff];
            #pragma unroll
            for (int g = 0; g < 4; ++g)
              acc[g][mt] = __builtin_amdgcn_mfma_f32_16x16x32_bf16(wfr[g], af, acc[g][mt], 0, 0, 0);
          }
        }
        #pragma unroll
        for (int mt = 0; mt < 4; ++mt){
          float hn[4];
          #pragma unroll
          for (int q = 0; q < 4; ++q)
            hn[q] = lstm_h(acc[0][mt][q], acc[1][mt][q], acc[2][mt][q], acc[3][mt][q], cst[mt * 4 + q]);
          uint2v pk;
          asm("v_cvt_pk_bf16_f32 %0, %1, %2" : "=v"(pk.x) : "v"(hn[0]), "v"(hn[1]));
          asm("v_cvt_pk_bf16_f32 %0, %1, %2" : "=v"(pk.y) : "v"(hn[2]), "v"(hn[3]));
          *(uint2v*)&A[(mt * 16 + l15) * AST + h1wr + jbase] = pk;   // h1(p-1)
        }
      }
    }

    // ====== head: t'' = p-2 (reads h1(p-2), stable region h1rd) ==========
    if (p >= 337){
      const int hreg = 128 + par * 64;   // h1(p-2) parity = p&1
      const short8 hv0 = *(const short8*)&A[hd_hs * AST + hreg + hd_part * 16];
      const short8 hv1 = *(const short8*)&A[hd_hs * AST + hreg + hd_part * 16 + 8];
      float pv = 0.f;
      #pragma unroll
      for (int jj = 0; jj < 8; ++jj){
        float a0 = fmaxf(bf2f((unsigned short)hv0[jj]), 0.f);
        float a1 = fmaxf(bf2f((unsigned short)hv1[jj]), 0.f);
        pv += a0 * HW[hd_outc * 64 + hd_part * 16 + jj];
        pv += a1 * HW[hd_outc * 64 + hd_part * 16 + 8 + jj];
      }
      pv += __shfl_xor(pv, 1);
      pv += __shfl_xor(pv, 2);
      if ((tid & 3) == 0){
        float val;
        if (hd_outc == 0) val = pv + hb0;
        else {
          float x = pv + hb1;   // softplus, stable
          val = fmaxf(x, 0.f) + __logf(1.f + __expf(-fabsf(x)));
        }
        outp[(((size_t)b * 48 + (p - 337)) * 512 + (n0 + hd_hs)) * 2 + hd_outc] = val;
      }
    }

    rCur = rNxt;
    // ONE barrier/phase: all LDS stores visible; no vmcnt drain (global
    // prefetch waits at its use next phase).
    asm volatile("s_waitcnt lgkmcnt(0)\n\ts_barrier" ::: "memory");
  }
}

extern "C" void kernel_launch(void* const* d_in, const int* in_sizes, int n_in,
                              void* d_out, int out_size, void* d_ws, size_t ws_size,
                              hipStream_t stream) {
  (void)in_sizes; (void)n_in; (void)out_size; (void)d_ws; (void)ws_size;
  deepar_kernel<<<dim3(256), dim3(512), 0, stream>>>(
      (const float*)d_in[0],  (const float*)d_in[1],
      (const float*)d_in[2],  (const float*)d_in[3],
      (const float*)d_in[4],  (const float*)d_in[5],
      (const float*)d_in[6],  (const float*)d_in[7],
      (const float*)d_in[8],  (const float*)d_in[9],
      (const float*)d_in[10], (const float*)d_in[11],
      (const float*)d_in[12], (const float*)d_in[13],
      (float*)d_out);
}